// Round 6
// baseline (531.502 us; speedup 1.0000x reference)
//
#include <hip/hip_runtime.h>

#define N_USERS 100000
#define N_ITEMS 50000
#define NEDGE   800000
#define NH      128
#define NHNH    16384
#define NTGT    8192
#define NNODE   250000      // 50K item slots (buys) + 100K user (rev) + 100K user (fol)
#define BASE_REV 50000
#define BASE_FOL 150000
#define NBUCK   588         // 196 buys (256 nodes) + 196 rev (512) + 196 fol (512)
#define NBLK    384         // binning blocks
#define NPB     6250        // edges per binning block: 384*6250 = 2400000 exactly
#define NRUN    (NBUCK * NBLK)        // 225792 per-(bucket,block) runs
#define NSCANB  441                   // 225792 / 512 exactly
#define PADCAP  4096        // per-bucket esrc slack for 8-padding (max 512*7+7=3591)
#define GRID_I  391         // (N_ITEMS+127)/128
#define GRID_U  782         // (N_USERS+127)/128
#define NPREP   9449        // prep blocks inside k_prep_count
#define AGGT_G  128         // 2*NTGT units / 128; k_agg_tgt grid = AGGT_G*8

typedef __attribute__((ext_vector_type(8))) short short8;
typedef __attribute__((ext_vector_type(4))) float f32x4;
typedef __attribute__((ext_vector_type(2))) float f32x2;

// ---------------------------------------------------------------- bf16 helpers (RNE, manual)
__device__ __forceinline__ unsigned rne_hi(float f) {
  unsigned u = __float_as_uint(f);
  u += 0x7FFFu + ((u >> 16) & 1u);
  return u & 0xFFFF0000u;
}
__device__ __forceinline__ unsigned pack2(float f0, float f1) {
  return (rne_hi(f0) >> 16) | rne_hi(f1);   // low ushort = f0, high = f1
}
__device__ __forceinline__ float blo(unsigned u) { return __uint_as_float(u << 16); }
__device__ __forceinline__ float bhi(unsigned u) { return __uint_as_float(u & 0xFFFF0000u); }

__device__ __forceinline__ int bucket_of(int n) {
  return (n < BASE_REV) ? (n >> 8)
       : (n < BASE_FOL) ? 196 + ((n - BASE_REV) >> 9)
                        : 392 + ((n - BASE_FOL) >> 9);
}

// W fragment-order permutation: output 16B chunk c (of 2048 per matrix) holds
// floats [fs, fs+8) so the GEMM's b[j] load (chunk (kcb*8+j)*64 + lane) is a
// fully coalesced 1KB wave read.  fs = row-major W[16j + (lane&15)][kc8*32 + (lane>>4)*8].
__device__ __forceinline__ int wperm_src(int c) {
  int lane = c & 63, j = (c >> 6) & 7, kc8 = c >> 9;
  return (16 * j + (lane & 15)) * 128 + kc8 * 32 + (lane >> 4) * 8;
}

// ---------------------------------------------------------------- fused prep + pass-A histogram (merged launches)
// block ranges: [0,6250) ub | [6250,9375) ib | [9375,9423) Wlb(perm) |
//               [9423,9431) Wrb00(perm) | [9431,9439) Wrc(linear)+Wrcb(perm) |
//               [9439,9447) Wrc1 | 9447 bc | 9448 zero rows | [9449,+NBLK) histogram
__global__ __launch_bounds__(256) void k_prep_count(
    const float* __restrict__ eu, const float* __restrict__ ei,
    const float* __restrict__ Wl, const float* __restrict__ Wr,
    const float* __restrict__ bl,
    unsigned* __restrict__ ub, unsigned* __restrict__ ib,
    unsigned* __restrict__ Wlb, unsigned* __restrict__ Wrb00,
    float* __restrict__ Wrc, unsigned* __restrict__ Wrcb, float* __restrict__ bc,
    unsigned* __restrict__ xub, unsigned* __restrict__ xib,
    const int* __restrict__ db, const int* __restrict__ dr,
    const int* __restrict__ df, int* __restrict__ cntBB)
{
  __shared__ int h[NBUCK];
  int b = blockIdx.x, t = threadIdx.x;
  if (b < 9375) {
    const float* src; unsigned* dst; int i;
    if (b < 6250)      { src = eu; dst = ub;    i = b * 256 + t; }
    else               { src = ei; dst = ib;    i = (b - 6250) * 256 + t; }
    const float4* xp = (const float4*)src;
    float4 a = xp[(size_t)i * 2];
    float4 c = xp[(size_t)i * 2 + 1];
    ((uint4*)dst)[i] = make_uint4(pack2(a.x, a.y), pack2(a.z, a.w),
                                  pack2(c.x, c.y), pack2(c.z, c.w));
  } else if (b < 9423) {
    // Wlb: 6 matrices, fragment-order permuted
    int i = (b - 9375) * 256 + t;          // [0, 12288)
    int m = i >> 11, c = i & 2047;
    const float4* p = (const float4*)(Wl + m * NHNH + wperm_src(c));
    float4 a = p[0], cc = p[1];
    ((uint4*)Wlb)[i] = make_uint4(pack2(a.x, a.y), pack2(a.z, a.w),
                                  pack2(cc.x, cc.y), pack2(cc.z, cc.w));
  } else if (b < 9431) {
    // Wrb00: permuted
    int i = (b - 9423) * 256 + t;          // [0, 2048)
    const float4* p = (const float4*)(Wr + wperm_src(i));
    float4 a = p[0], cc = p[1];
    ((uint4*)Wrb00)[i] = make_uint4(pack2(a.x, a.y), pack2(a.z, a.w),
                                    pack2(cc.x, cc.y), pack2(cc.z, cc.w));
  } else if (b < 9439) {
    int i = (b - 9431) * 256 + t;          // [0, 2048)
    // Wrc: LINEAR f32 combine (consumed by k_gemm_mlp)
    const float4* w1 = (const float4*)(Wr + 1 * NHNH);
    const float4* w2 = (const float4*)(Wr + 2 * NHNH);
    float4 a1 = w1[(size_t)i * 2],     a2 = w2[(size_t)i * 2];
    float4 c1 = w1[(size_t)i * 2 + 1], c2 = w2[(size_t)i * 2 + 1];
    ((float4*)Wrc)[(size_t)i * 2] =
        make_float4(a1.x + a2.x, a1.y + a2.y, a1.z + a2.z, a1.w + a2.w);
    ((float4*)Wrc)[(size_t)i * 2 + 1] =
        make_float4(c1.x + c2.x, c1.y + c2.y, c1.z + c2.z, c1.w + c2.w);
    // Wrcb: permuted bf16 combine (consumed by k_l1)
    int fs = wperm_src(i);
    const float4* p1 = (const float4*)(Wr + 1 * NHNH + fs);
    const float4* p2 = (const float4*)(Wr + 2 * NHNH + fs);
    float4 pa = p1[0], pc = p1[1], qa = p2[0], qc = p2[1];
    float4 sa = make_float4(pa.x + qa.x, pa.y + qa.y, pa.z + qa.z, pa.w + qa.w);
    float4 sc = make_float4(pc.x + qc.x, pc.y + qc.y, pc.z + qc.z, pc.w + qc.w);
    ((uint4*)Wrcb)[i] = make_uint4(pack2(sa.x, sa.y), pack2(sa.z, sa.w),
                                   pack2(sc.x, sc.y), pack2(sc.z, sc.w));
  } else if (b < 9447) {
    int i = (b - 9439) * 256 + t;
    const float4* w1 = (const float4*)(Wr + 4 * NHNH);
    const float4* w2 = (const float4*)(Wr + 5 * NHNH);
    float4 a1 = w1[(size_t)i * 2],     a2 = w2[(size_t)i * 2];
    float4 c1 = w1[(size_t)i * 2 + 1], c2 = w2[(size_t)i * 2 + 1];
    ((float4*)(Wrc + NHNH))[(size_t)i * 2] =
        make_float4(a1.x + a2.x, a1.y + a2.y, a1.z + a2.z, a1.w + a2.w);
    ((float4*)(Wrc + NHNH))[(size_t)i * 2 + 1] =
        make_float4(c1.x + c2.x, c1.y + c2.y, c1.z + c2.z, c1.w + c2.w);
  } else if (b == 9447) {
    if (t < NH)       bc[t]      = bl[1 * NH + t] + bl[2 * NH + t];
    else if (t < 2*NH) { int r = t - NH; bc[NH + r] = bl[4 * NH + r] + bl[5 * NH + r]; }
  } else if (b == 9448) {
    // zero pad rows: ub[N_USERS], ib[N_ITEMS], xu1b[N_USERS], xi1b[N_ITEMS]
    if (t < 64) {
      int row = t >> 4, q = t & 15;
      uint4 z = make_uint4(0u, 0u, 0u, 0u);
      uint4* p = (row == 0) ? (uint4*)ub  + (size_t)N_USERS * 16
               : (row == 1) ? (uint4*)ib  + (size_t)N_ITEMS * 16
               : (row == 2) ? (uint4*)xub + (size_t)N_USERS * 16
                            : (uint4*)xib + (size_t)N_ITEMS * 16;
      p[q] = z;
    }
  } else {
    // ---- pass A histogram, blk = b - NPREP
    int blk = b - NPREP;
    for (int j = t; j < NBUCK; j += 256) h[j] = 0;
    __syncthreads();
    int ebase = blk * NPB;
    for (int i = t; i < NPB; i += 256) {
      int e = ebase + i, n;
      if (e < NEDGE)          n = db[e];
      else if (e < 2 * NEDGE) n = BASE_REV + dr[e - NEDGE];
      else                    n = BASE_FOL + df[e - 2 * NEDGE];
      atomicAdd(&h[bucket_of(n)], 1);
    }
    __syncthreads();
    for (int j = t; j < NBUCK; j += 256) cntBB[j * NBLK + blk] = h[j];
  }
}

// ---------------------------------------------------------------- single-kernel scan of 225792 counts
__global__ __launch_bounds__(256) void k_scan(const int* __restrict__ cntBB,
                                              int* __restrict__ sscan)
{
  int t = threadIdx.x, blk = blockIdx.x;
  int base = blk * 512;
  int lane = t & 63, w = t >> 6;
  int Ps = 0;
  for (int i = t * 4; i + 3 < base; i += 1024) {
    int4 v = *(const int4*)&cntBB[i];
    Ps += v.x + v.y + v.z + v.w;
  }
  #pragma unroll
  for (int o = 32; o > 0; o >>= 1) Ps += __shfl_xor(Ps, o);
  __shared__ int red[4];
  if (lane == 0) red[w] = Ps;
  __syncthreads();
  int P = red[0] + red[1] + red[2] + red[3];
  int a0 = cntBB[base + t * 2], a1 = cntBB[base + t * 2 + 1];
  int sum = a0 + a1;
  int v = sum;
  #pragma unroll
  for (int o = 1; o < 64; o <<= 1) { int u = __shfl_up(v, o); if (lane >= o) v += u; }
  __shared__ int wsum[4];
  if (lane == 63) wsum[w] = v;
  __syncthreads();
  int wb = 0;
  for (int i = 0; i < w; ++i) wb += wsum[i];
  int excl = wb + v - sum;
  sscan[base + t * 2]     = P + excl;
  sscan[base + t * 2 + 1] = P + excl + a0;
  if (blk == NSCANB - 1 && t == 255)
    sscan[NRUN] = P + wsum[0] + wsum[1] + wsum[2] + wsum[3];   // == 3*NEDGE
}

// ---------------------------------------------------------------- pass B: scatter into pre-reserved runs (LDS cursors only)
__global__ __launch_bounds__(256) void k_pfill(
    const int* __restrict__ sb, const int* __restrict__ db,
    const int* __restrict__ sr, const int* __restrict__ dr,
    const int* __restrict__ sf, const int* __restrict__ df,
    const int* __restrict__ sscan, int* __restrict__ binned)
{
  __shared__ int cur[NBUCK];
  int t = threadIdx.x, blk = blockIdx.x;
  for (int j = t; j < NBUCK; j += 256) cur[j] = sscan[j * NBLK + blk];
  __syncthreads();
  int ebase = blk * NPB;
  for (int i = t; i < NPB; i += 256) {
    int e = ebase + i, n, s;
    if (e < NEDGE)          { n = db[e];                      s = sb[e]; }
    else if (e < 2 * NEDGE) { n = BASE_REV + dr[e - NEDGE];   s = sr[e - NEDGE]; }
    else                    { n = BASE_FOL + df[e - 2*NEDGE]; s = sf[e - 2*NEDGE]; }
    int b = bucket_of(n);
    int local = (n < BASE_REV) ? (n & 255)
              : (n < BASE_FOL) ? ((n - BASE_REV) & 511)
                               : ((n - BASE_FOL) & 511);
    int pos = atomicAdd(&cur[b], 1);
    binned[pos] = (local << 17) | s;
  }
}

// ---------------------------------------------------------------- pass C: per-bucket PADDED CSR build (1 block / bucket)
__global__ __launch_bounds__(256) void k_csr(
    const int* __restrict__ binned, const int* __restrict__ sscan,
    int* __restrict__ cnt, int* __restrict__ offs, int* __restrict__ esrc)
{
  int b = blockIdx.x;
  int n0, S, zpad;
  if (b < 196)      { n0 = b * 256;                    S = min(256, BASE_REV - n0); zpad = N_USERS; }
  else if (b < 392) { n0 = BASE_REV + (b - 196) * 512; S = min(512, BASE_FOL - n0); zpad = N_ITEMS; }
  else              { n0 = BASE_FOL + (b - 392) * 512; S = min(512, NNODE - n0);    zpad = N_USERS; }
  int e0 = sscan[b * NBLK];
  int e1 = sscan[(b + 1) * NBLK];
  int e0p = ((e0 + 7) & ~7) + b * PADCAP;   // 8-aligned padded region base
  int t = threadIdx.x;
  __shared__ int h[512], fl[512];
  __shared__ int wsum[4];
  h[t] = 0; h[t + 256] = 0;
  __syncthreads();
  for (int e = e0 + t; e < e1; e += 256)
    atomicAdd(&h[binned[e] >> 17], 1);
  __syncthreads();
  int a0 = h[t * 2], a1 = h[t * 2 + 1];
  int p0 = (a0 + 7) & ~7, p1 = (a1 + 7) & ~7;   // padded counts (0 stays 0)
  int v = p0 + p1;
  int lane = t & 63, w = t >> 6;
  #pragma unroll
  for (int o = 1; o < 64; o <<= 1) { int u = __shfl_up(v, o); if (lane >= o) v += u; }
  if (lane == 63) wsum[w] = v;
  __syncthreads();
  int wb = 0;
  for (int i = 0; i < w; ++i) wb += wsum[i];
  int excl = wb + v - (p0 + p1);
  int ps0 = e0p + excl, ps1 = e0p + excl + p0;
  fl[t * 2]     = ps0;
  fl[t * 2 + 1] = ps1;
  if (t * 2 < S)     { cnt[n0 + t * 2]     = a0; offs[n0 + t * 2]     = ps0; }
  if (t * 2 + 1 < S) { cnt[n0 + t * 2 + 1] = a1; offs[n0 + t * 2 + 1] = ps1; }
  __syncthreads();
  for (int e = e0 + t; e < e1; e += 256) {
    int v2 = binned[e];
    int p = atomicAdd(&fl[v2 >> 17], 1);
    esrc[p] = v2 & 0x1FFFF;
  }
  __syncthreads();
  for (int e = ps0 + a0; e < ps0 + p0; ++e) esrc[e] = zpad;
  for (int e = ps1 + a1; e < ps1 + p1; ++e) esrc[e] = zpad;
}

// ---------------------------------------------------------------- FUSED layer-1: gather-mean -> LDS (swizzled) -> MFMA -> LN -> bf16 out
// Block-cooperative gather (16 streams x 16 lanes, chunk-8 padded CSR) writes
// bf16 means straight into the swizzled MFMA A-tile; no meanL1b round-trip.

// gather 128 rows' mean into LDS. LDS[rb][c] = mean[rb][c ^ (rb&7)] (16B chunks).
__device__ __forceinline__ void gather_mean_128(
    const int* __restrict__ offs, const int* __restrict__ cnt,
    const int* __restrict__ esrc, const uint4* __restrict__ table,
    int slot_base, int gmax, int bx, uint4* As16, int t)
{
  int sid = t >> 4, sl = t & 15;
  for (int i = 0; i < 8; ++i) {
    int rb = i * 16 + sid;
    int gr = bx * 128 + rb; if (gr > gmax) gr = gmax;
    int n = slot_base + gr;
    int st = offs[n], c = cnt[n];
    int nch = (c + 7) >> 3;
    f32x2 a0 = {0.f, 0.f}, a1 = {0.f, 0.f}, a2 = {0.f, 0.f}, a3 = {0.f, 0.f};
    for (int ch = 0; ch < nch; ++ch) {
      int4 sA = *(const int4*)&esrc[st + ch * 8];
      int4 sB = *(const int4*)&esrc[st + ch * 8 + 4];
      uint4 v0 = table[(size_t)sA.x * 16 + sl];
      uint4 v1 = table[(size_t)sA.y * 16 + sl];
      uint4 v2 = table[(size_t)sA.z * 16 + sl];
      uint4 v3 = table[(size_t)sA.w * 16 + sl];
      uint4 v4 = table[(size_t)sB.x * 16 + sl];
      uint4 v5 = table[(size_t)sB.y * 16 + sl];
      uint4 v6 = table[(size_t)sB.z * 16 + sl];
      uint4 v7 = table[(size_t)sB.w * 16 + sl];
      a0 += (f32x2){blo(v0.x), bhi(v0.x)} + (f32x2){blo(v1.x), bhi(v1.x)}
          + (f32x2){blo(v2.x), bhi(v2.x)} + (f32x2){blo(v3.x), bhi(v3.x)}
          + (f32x2){blo(v4.x), bhi(v4.x)} + (f32x2){blo(v5.x), bhi(v5.x)}
          + (f32x2){blo(v6.x), bhi(v6.x)} + (f32x2){blo(v7.x), bhi(v7.x)};
      a1 += (f32x2){blo(v0.y), bhi(v0.y)} + (f32x2){blo(v1.y), bhi(v1.y)}
          + (f32x2){blo(v2.y), bhi(v2.y)} + (f32x2){blo(v3.y), bhi(v3.y)}
          + (f32x2){blo(v4.y), bhi(v4.y)} + (f32x2){blo(v5.y), bhi(v5.y)}
          + (f32x2){blo(v6.y), bhi(v6.y)} + (f32x2){blo(v7.y), bhi(v7.y)};
      a2 += (f32x2){blo(v0.z), bhi(v0.z)} + (f32x2){blo(v1.z), bhi(v1.z)}
          + (f32x2){blo(v2.z), bhi(v2.z)} + (f32x2){blo(v3.z), bhi(v3.z)}
          + (f32x2){blo(v4.z), bhi(v4.z)} + (f32x2){blo(v5.z), bhi(v5.z)}
          + (f32x2){blo(v6.z), bhi(v6.z)} + (f32x2){blo(v7.z), bhi(v7.z)};
      a3 += (f32x2){blo(v0.w), bhi(v0.w)} + (f32x2){blo(v1.w), bhi(v1.w)}
          + (f32x2){blo(v2.w), bhi(v2.w)} + (f32x2){blo(v3.w), bhi(v3.w)}
          + (f32x2){blo(v4.w), bhi(v4.w)} + (f32x2){blo(v5.w), bhi(v5.w)}
          + (f32x2){blo(v6.w), bhi(v6.w)} + (f32x2){blo(v7.w), bhi(v7.w)};
    }
    float inv = 1.0f / fmaxf((float)c, 1.0f);
    As16[rb * 16 + (sl ^ (rb & 7))] =
        make_uint4(pack2(a0.x * inv, a0.y * inv), pack2(a1.x * inv, a1.y * inv),
                   pack2(a2.x * inv, a2.y * inv), pack2(a3.x * inv, a3.y * inv));
  }
}

// one GEMM term: acc += A_lds * W^T  (A from swizzled LDS, W pre-permuted)
__device__ __forceinline__ void mfma_term(
    const unsigned short* __restrict__ W, const unsigned short* smem,
    int wv, int lane, f32x4 (&acc)[2][8])
{
  int quad = lane >> 4, c0 = lane & 15, xr = c0 & 7;
  const unsigned short* As_w = smem + wv * 4096;
  #pragma unroll
  for (int kcb = 0; kcb < 4; ++kcb) {
    short8 b[8];
    #pragma unroll
    for (int j = 0; j < 8; ++j)
      b[j] = *(const short8*)(W + (((kcb * 8 + j) << 6) + lane) * 8);
    int cg = (kcb << 2) + quad;
    short8 a0 = *(const short8*)(As_w + c0 * 128        + ((cg ^ xr) << 3));
    short8 a1 = *(const short8*)(As_w + (c0 + 16) * 128 + ((cg ^ xr) << 3));
    #pragma unroll
    for (int j = 0; j < 8; ++j) {
      acc[0][j] = __builtin_amdgcn_mfma_f32_16x16x32_bf16(a0, b[j], acc[0][j], 0, 0, 0);
      acc[1][j] = __builtin_amdgcn_mfma_f32_16x16x32_bf16(a1, b[j], acc[1][j], 0, 0, 0);
    }
  }
}

// stage 32 contiguous bf16 rows (x0 term) per wave via global_load_lds, swizzled src
__device__ __forceinline__ void stage_tile(const unsigned short* __restrict__ Ag,
                                           unsigned short* As_w, int R0w,
                                           int quad, int c0)
{
  #pragma unroll
  for (int r = 0; r < 8; ++r) {
    int swz = c0 ^ (4 * (r & 1) + quad);       // chunk ^ (row&7)
    const unsigned short* g = Ag + (size_t)(R0w + r * 4 + quad) * NH + (swz << 3);
    __builtin_amdgcn_global_load_lds(
        (const __attribute__((address_space(1))) void*)g,
        (__attribute__((address_space(3))) void*)(As_w + r * 512),
        16, 0, 0);
  }
}

__device__ __forceinline__ void l1_body(
    int bx, int is_item,
    const int* __restrict__ offs, const int* __restrict__ cnt,
    const int* __restrict__ esrc,
    const uint4* __restrict__ ub4, const uint4* __restrict__ ib4,
    const unsigned short* __restrict__ WA, const unsigned short* __restrict__ WB,
    const unsigned short* __restrict__ Wr,
    const float* __restrict__ bias, const float* __restrict__ lng,
    const float* __restrict__ lnb, unsigned short* __restrict__ out, int M,
    unsigned short* smem)
{
  const int t = threadIdx.x;
  const int wv = t >> 6, lane = t & 63;
  const int quad = lane >> 4, c0 = lane & 15;
  uint4* As16 = (uint4*)smem;
  unsigned short* As_w = smem + wv * 4096;
  const int R0w = bx * 128 + wv * 32;

  f32x4 acc[2][8];
  #pragma unroll
  for (int i = 0; i < 2; ++i)
    #pragma unroll
    for (int j = 0; j < 8; ++j) acc[i][j] = (f32x4){0.f, 0.f, 0.f, 0.f};

  // term 1: mean over first edge type
  if (is_item) gather_mean_128(offs, cnt, esrc, ub4, 0,        M - 1, bx, As16, t);
  else         gather_mean_128(offs, cnt, esrc, ib4, BASE_REV, M - 1, bx, As16, t);
  __syncthreads();
  mfma_term(WA, smem, wv, lane, acc);

  if (!is_item) {
    __syncthreads();      // all waves' ds_reads done before gather-2 overwrites
    gather_mean_128(offs, cnt, esrc, ub4, BASE_FOL, M - 1, bx, As16, t);
    __syncthreads();
    mfma_term(WB, smem, wv, lane, acc);
  }

  // Wr term: stage this wave's own x0 rows (others never read them)
  asm volatile("s_waitcnt lgkmcnt(0)" ::: "memory");
  __builtin_amdgcn_sched_barrier(0);
  stage_tile(is_item ? (const unsigned short*)ib4 : (const unsigned short*)ub4,
             As_w, R0w, quad, c0);
  asm volatile("s_waitcnt vmcnt(0)" ::: "memory");
  __builtin_amdgcn_sched_barrier(0);
  mfma_term(Wr, smem, wv, lane, acc);

  __syncthreads();   // all reads of As done (ytile aliases stage regions)

  float bb[8], gg[8], ll[8];
  #pragma unroll
  for (int j = 0; j < 8; ++j) {
    bb[j] = bias[16 * j + c0]; gg[j] = lng[16 * j + c0]; ll[j] = lnb[16 * j + c0];
  }

  unsigned short* yt = smem + wv * 4224;       // ytile[wv][32][132]
  #pragma unroll
  for (int i = 0; i < 2; ++i) {
    #pragma unroll
    for (int r = 0; r < 4; ++r) {
      float v[8]; float s = 0.f, ss = 0.f;
      #pragma unroll
      for (int j = 0; j < 8; ++j) {
        float x = acc[i][j][r] + bb[j];
        v[j] = x; s += x; ss += x * x;
      }
      #pragma unroll
      for (int o = 1; o < 16; o <<= 1) { s += __shfl_xor(s, o); ss += __shfl_xor(ss, o); }
      float mu = s * (1.0f / 128.0f);
      float var = ss * (1.0f / 128.0f) - mu * mu;
      float rinv = rsqrtf(var + 1e-5f);
      int rl = 16 * i + quad * 4 + r;
      #pragma unroll
      for (int j = 0; j < 8; ++j) {
        float y = fmaxf((v[j] - mu) * rinv * gg[j] + ll[j], 0.f);
        yt[rl * 132 + 16 * j + c0] = (unsigned short)(rne_hi(y) >> 16);
      }
    }
  }
  __syncthreads();
  #pragma unroll
  for (int it = 0; it < 16; ++it) {
    int idx = it * 256 + t;
    int row = idx >> 5, c4 = (idx & 31) * 4;
    int gr = bx * 128 + row;
    if (gr < M)
      *(uint2*)(out + (size_t)gr * NH + c4) =
          *(const uint2*)(smem + (row >> 5) * 4224 + (row & 31) * 132 + c4);
  }
}

// merged launch: blocks [0,GRID_I) items, [GRID_I, GRID_I+GRID_U) users
__global__ __launch_bounds__(256) void k_l1(
    const int* __restrict__ offs, const int* __restrict__ cnt,
    const int* __restrict__ esrc,
    const uint4* __restrict__ ub4, const uint4* __restrict__ ib4,
    const unsigned short* __restrict__ Wlb,
    const unsigned short* __restrict__ Wrb00,
    const unsigned short* __restrict__ Wrcb,
    const float* __restrict__ ibias, const float* __restrict__ ilng,
    const float* __restrict__ ilnb, unsigned short* __restrict__ xi1b,
    const float* __restrict__ ubias, const float* __restrict__ ulng,
    const float* __restrict__ ulnb, unsigned short* __restrict__ xu1b)
{
  __shared__ uint4 smemv[2112];                // 33792 B
  unsigned short* smem = (unsigned short*)smemv;
  int b = blockIdx.x;
  if (b < GRID_I)
    l1_body(b, 1, offs, cnt, esrc, ub4, ib4,
            Wlb + 0 * NHNH, nullptr, Wrb00,
            ibias, ilng, ilnb, xi1b, N_ITEMS, smem);
  else
    l1_body(b - GRID_I, 0, offs, cnt, esrc, ub4, ib4,
            Wlb + 1 * NHNH, Wlb + 2 * NHNH, Wrcb,
            ubias, ulng, ulnb, xu1b, N_USERS, smem);
}

// ---------------------------------------------------------------- layer-2 target aggregation (XCD feature-split)
__global__ __launch_bounds__(256) void k_agg_tgt(
    const int* __restrict__ tgt, const int* __restrict__ offs,
    const int* __restrict__ cnt, const int* __restrict__ esrc,
    const uint4* __restrict__ xu1b4, const uint4* __restrict__ xi1b4,
    float* __restrict__ mrev, float* __restrict__ mfol, float* __restrict__ xsel)
{
  int bid = blockIdx.x;
  int x = bid & 7, g = bid >> 3;
  int half = x >> 2, sub = x & 3;
  int sid = threadIdx.x >> 3, ln = threadIdx.x & 7;
  int unit = (g * 4 + sub) * 32 + sid;   // [0, 2*NTGT)
  int tg = unit >> 1, which = unit & 1;
  int u = tgt[tg];
  int n = (which ? BASE_FOL : BASE_REV) + u;
  const uint4* table = which ? xu1b4 : xi1b4;
  int sl = half * 8 + ln;
  int st = offs[n], c = cnt[n];
  int nch = (c + 7) >> 3;
  f32x2 a0 = {0.f, 0.f}, a1 = {0.f, 0.f}, a2 = {0.f, 0.f}, a3 = {0.f, 0.f};
  for (int ch = 0; ch < nch; ++ch) {
    int4 sA = *(const int4*)&esrc[st + ch * 8];
    int4 sB = *(const int4*)&esrc[st + ch * 8 + 4];
    uint4 v0 = table[(size_t)sA.x * 16 + sl];
    uint4 v1 = table[(size_t)sA.y * 16 + sl];
    uint4 v2 = table[(size_t)sA.z * 16 + sl];
    uint4 v3 = table[(size_t)sA.w * 16 + sl];
    uint4 v4 = table[(size_t)sB.x * 16 + sl];
    uint4 v5 = table[(size_t)sB.y * 16 + sl];
    uint4 v6 = table[(size_t)sB.z * 16 + sl];
    uint4 v7 = table[(size_t)sB.w * 16 + sl];
    a0 += (f32x2){blo(v0.x), bhi(v0.x)} + (f32x2){blo(v1.x), bhi(v1.x)}
        + (f32x2){blo(v2.x), bhi(v2.x)} + (f32x2){blo(v3.x), bhi(v3.x)}
        + (f32x2){blo(v4.x), bhi(v4.x)} + (f32x2){blo(v5.x), bhi(v5.x)}
        + (f32x2){blo(v6.x), bhi(v6.x)} + (f32x2){blo(v7.x), bhi(v7.x)};
    a1 += (f32x2){blo(v0.y), bhi(v0.y)} + (f32x2){blo(v1.y), bhi(v1.y)}
        + (f32x2){blo(v2.y), bhi(v2.y)} + (f32x2){blo(v3.y), bhi(v3.y)}
        + (f32x2){blo(v4.y), bhi(v4.y)} + (f32x2){blo(v5.y), bhi(v5.y)}
        + (f32x2){blo(v6.y), bhi(v6.y)} + (f32x2){blo(v7.y), bhi(v7.y)};
    a2 += (f32x2){blo(v0.z), bhi(v0.z)} + (f32x2){blo(v1.z), bhi(v1.z)}
        + (f32x2){blo(v2.z), bhi(v2.z)} + (f32x2){blo(v3.z), bhi(v3.z)}
        + (f32x2){blo(v4.z), bhi(v4.z)} + (f32x2){blo(v5.z), bhi(v5.z)}
        + (f32x2){blo(v6.z), bhi(v6.z)} + (f32x2){blo(v7.z), bhi(v7.z)};
    a3 += (f32x2){blo(v0.w), bhi(v0.w)} + (f32x2){blo(v1.w), bhi(v1.w)}
        + (f32x2){blo(v2.w), bhi(v2.w)} + (f32x2){blo(v3.w), bhi(v3.w)}
        + (f32x2){blo(v4.w), bhi(v4.w)} + (f32x2){blo(v5.w), bhi(v5.w)}
        + (f32x2){blo(v6.w), bhi(v6.w)} + (f32x2){blo(v7.w), bhi(v7.w)};
  }
  float inv = 1.0f / fmaxf((float)c, 1.0f);
  float4 o0 = make_float4(a0.x * inv, a0.y * inv, a1.x * inv, a1.y * inv);
  float4 o1 = make_float4(a2.x * inv, a2.y * inv, a3.x * inv, a3.y * inv);
  float* outp = which ? mfol : mrev;
  ((float4*)outp)[(size_t)tg * 32 + sl * 2]     = o0;
  ((float4*)outp)[(size_t)tg * 32 + sl * 2 + 1] = o1;
  if (!which) {
    uint4 xv = xu1b4[(size_t)u * 16 + sl];
    ((float4*)xsel)[(size_t)tg * 32 + sl * 2] =
        make_float4(blo(xv.x), bhi(xv.x), blo(xv.y), bhi(xv.y));
    ((float4*)xsel)[(size_t)tg * 32 + sl * 2 + 1] =
        make_float4(blo(xv.z), bhi(xv.z), blo(xv.w), bhi(xv.w));
  }
}

// ---------------------------------------------------------------- fp32 GEMM + bias + LN + ReLU + fused final MLP
__global__ __launch_bounds__(256) void k_gemm_mlp(
    const float* __restrict__ A0, const float* __restrict__ W0,
    const float* __restrict__ A1, const float* __restrict__ W1,
    const float* __restrict__ A2, const float* __restrict__ W2,
    const float* __restrict__ bias, const float* __restrict__ lng,
    const float* __restrict__ lnb,
    const float* __restrict__ W1m, const float* __restrict__ b1m,
    const float* __restrict__ W2m, const float* __restrict__ b2m,
    float* __restrict__ out, int M)
{
  __shared__ float smem[12800];
  float* As  = smem;              // [32][68]
  float* Ws  = smem + 2176;       // [4224]
  float* hs  = smem;              // [64][132] (MLP phase)
  float* W1s = smem + 8448;       // [32][132]
  float* b1s = smem + 12672;      // [64]
  float* W2s = smem + 12736;      // [64]

  const int t = threadIdx.x;
  const int tx = t & 31, ty = t >> 5;
  const int rowbase = blockIdx.x * 64;

  float acc[8][4];
  #pragma unroll
  for (int i = 0; i < 8; ++i)
    #pragma unroll
    for (int j = 0; j < 4; ++j) acc[i][j] = 0.f;

  const int arow = t >> 2;
  const int ak8  = (t & 3) * 8;

  #pragma unroll
  for (int term = 0; term < 3; ++term) {
    const float* A = (term == 0) ? A0 : (term == 1) ? A1 : A2;
    const float* W = (term == 0) ? W0 : (term == 1) ? W1 : W2;
    if (A == nullptr) continue;
    for (int kc = 0; kc < NH; kc += 32) {
      {
        int gr = rowbase + arow; if (gr > M - 1) gr = M - 1;
        const float* ap = &A[(size_t)gr * NH + kc + ak8];
        float4 v0 = *(const float4*)(ap);
        float4 v1 = *(const float4*)(ap + 4);
        As[(ak8 + 0) * 68 + arow] = v0.x; As[(ak8 + 1) * 68 + arow] = v0.y;
        As[(ak8 + 2) * 68 + arow] = v0.z; As[(ak8 + 3) * 68 + arow] = v0.w;
        As[(ak8 + 4) * 68 + arow] = v1.x; As[(ak8 + 5) * 68 + arow] = v1.y;
        As[(ak8 + 6) * 68 + arow] = v1.z; As[(ak8 + 7) * 68 + arow] = v1.w;
      }
      #pragma unroll
      for (int i = 0; i < 4; ++i) {
        int linear = t * 4 + i * 1024;
        int j = linear >> 5, k4 = linear & 31;
        float4 v = *(const float4*)&W[j * NH + kc + k4];
        Ws[(k4 + 0) * 132 + j] = v.x; Ws[(k4 + 1) * 132 + j] = v.y;
        Ws[(k4 + 2) * 132 + j] = v.z; Ws[(k4 + 3) * 132 + j] = v.w;
      }
      __syncthreads();
      #pragma unroll
      for (int kk = 0; kk < 32; ++kk) {
        float4 alo = *(const float4*)&As[kk * 68 + ty * 8];
        float4 ahi = *(const float4*)&As[kk * 68 + ty * 8 + 4];
        float4 w4  = *(const float4*)&Ws[kk * 132 + tx * 4];
        float ar[8] = {alo.x, alo.y, alo.z, alo.w, ahi.x, ahi.y, ahi.z, ahi.w};
        float wr[4] = {w4.x, w4.y, w4.z, w4.w};
        #pragma unroll
        for (int i = 0; i < 8; ++i)
          #pragma unroll
          for (int j = 0; j < 4; ++j)
            acc[i][j] = fmaf(ar[i], wr[j], acc[i][j]);
      }
      __syncthreads();
    }
  }

  float4 b4 = *(const float4*)&bias[tx * 4];
  float4 g4 = *(const float4*)&lng[tx * 4];
  float4 l4 = *(const float4*)&lnb[tx * 4];
  float bb[4] = {b4.x, b4.y, b4.z, b4.w};
  float gg[4] = {g4.x, g4.y, g4.z, g4.w};
  float ll[4] = {l4.x, l4.y, l4.z, l4.w};

  #pragma unroll
  for (int i = 0; i < 8; ++i) {
    float s = 0.f, ss = 0.f;
    #pragma unroll
    for (int j = 0; j < 4; ++j) {
      float v = acc[i][j] + bb[j];
      acc[i][j] = v;
      s += v; ss += v * v;
    }
    #pragma unroll
    for (int o = 1; o < 32; o <<= 1) { s += __shfl_xor(s, o); ss += __shfl_xor(ss, o); }
    float mu = s * (1.0f / 128.0f);
    float var = ss * (1.0f / 128.0f) - mu * mu;
    float rinv = rsqrtf(var + 1e-5f);
    float* hp = &hs[(ty * 8 + i) * 132 + tx * 4];
    hp[0] = fmaxf((acc[i][0] - mu) * rinv * gg[0] + ll[0], 0.f);
    hp[1] = fmaxf((acc[i][1] - mu) * rinv * gg[1] + ll[1], 0.f);
    hp[2] = fmaxf((acc[i][2] - mu) * rinv * gg[2] + ll[2], 0.f);
    hp[3] = fmaxf((acc[i][3] - mu) * rinv * gg[3] + ll[3], 0.f);
  }
  if (t < 64) { b1s[t] = b1m[t]; W2s[t] = W2m[t]; }
  float b2v = b2m[0];

  int row = t >> 2, j = t & 3;
  float p = 0.f;
  #pragma unroll
  for (int half = 0; half < 2; ++half) {
    __syncthreads();
    #pragma unroll
    for (int i = 0; i < 16; ++i) {
      int idx = t + 256 * i;
      int j2 = idx >> 7, k2 = idx & 127;
      W1s[j2 * 132 + k2] = W1m[(half * 32 + j2) * 128 + k2];
    }
    __syncthreads();
    #pragma unroll
    for (int uu = 0; uu < 8; ++uu) {
      int ul = uu * 4 + j;
      float hacc = b1s[half * 32 + ul];
      const float* wrow = &W1s[ul * 132];
      const float* hrow = &hs[row * 132];
      #pragma unroll
      for (int k4 = 0; k4 < 32; ++k4) {
        float4 hv = *(const float4*)&hrow[k4 * 4];
        float4 wv = *(const float4*)&wrow[k4 * 4];
        hacc = fmaf(hv.x, wv.x, hacc);
        hacc = fmaf(hv.y, wv.y, hacc);
        hacc = fmaf(hv.z, wv.z, hacc);
        hacc = fmaf(hv.w, wv.w, hacc);
      }
      p += fmaxf(hacc, 0.f) * W2s[half * 32 + ul];
    }
  }
  p += __shfl_xor(p, 1);
  p += __shfl_xor(p, 2);
  if (j == 0) out[rowbase + row] = p + b2v;
}

// ---------------------------------------------------------------- launch
extern "C" void kernel_launch(void* const* d_in, const int* in_sizes, int n_in,
                              void* d_out, int out_size, void* d_ws, size_t ws_size,
                              hipStream_t stream)
{
  const float* emb_user = (const float*)d_in[0];
  const float* emb_item = (const float*)d_in[1];
  const float* Wl   = (const float*)d_in[2];   // [2,3,128,128]
  const float* bl   = (const float*)d_in[3];   // [2,3,128]
  const float* Wr   = (const float*)d_in[4];   // [2,3,128,128]
  const float* ln_g = (const float*)d_in[5];   // [2,2,128]
  const float* ln_b = (const float*)d_in[6];   // [2,2,128]
  const float* W1   = (const float*)d_in[7];   // [64,128]
  const float* b1   = (const float*)d_in[8];   // [64]
  const float* W2   = (const float*)d_in[9];   // [1,64]
  const float* b2   = (const float*)d_in[10];  // [1]
  const int* src_buys = (const int*)d_in[11];
  const int* dst_buys = (const int*)d_in[12];
  const int* src_rev  = (const int*)d_in[13];
  const int* dst_rev  = (const int*)d_in[14];
  const int* src_fol  = (const int*)d_in[15];
  const int* dst_fol  = (const int*)d_in[16];
  const int* tgt      = (const int*)d_in[17];
  float* outp = (float*)d_out;

  char* wp = (char*)d_ws;
  size_t ob = 0;
  auto take = [&](size_t bytes) -> void* {
    void* p = wp + ob;
    ob += (bytes + 255) & ~(size_t)255;
    return p;
  };
  int*            cnt     = (int*)           take((size_t)NNODE * 4);
  int*            offs    = (int*)           take((size_t)NNODE * 4);
  int*            cntBB   = (int*)           take((size_t)NRUN * 4);
  int*            sscan   = (int*)           take((size_t)(NRUN + 1) * 4);
  int*            esrc    = (int*)           take((size_t)(3 * NEDGE + (NBUCK + 1) * PADCAP) * 4);
  int*            binned  = (int*)           take((size_t)3 * NEDGE * 4);
  float*          Wrc     = (float*)         take((size_t)2 * NHNH * 4);
  float*          bc      = (float*)         take((size_t)2 * NH * 4);
  // +1 zero pad row on each gather table (index N_USERS / N_ITEMS)
  unsigned short* ub      = (unsigned short*)take((size_t)(N_USERS + 1) * NH * 2);
  unsigned short* ib      = (unsigned short*)take((size_t)(N_ITEMS + 1) * NH * 2);
  unsigned short* xu1b    = (unsigned short*)take((size_t)(N_USERS + 1) * NH * 2);
  unsigned short* xi1b    = (unsigned short*)take((size_t)(N_ITEMS + 1) * NH * 2);
  unsigned short* Wlb     = (unsigned short*)take((size_t)6 * NHNH * 2);
  unsigned short* Wrb00   = (unsigned short*)take((size_t)NHNH * 2);
  unsigned short* Wrcb    = (unsigned short*)take((size_t)NHNH * 2);
  float*          mrev2   = (float*)         take((size_t)NTGT * NH * 4);
  float*          mfol2   = (float*)         take((size_t)NTGT * NH * 4);
  float*          xsel2   = (float*)         take((size_t)NTGT * NH * 4);

  k_prep_count<<<NPREP + NBLK, 256, 0, stream>>>(emb_user, emb_item, Wl, Wr, bl,
      (unsigned*)ub, (unsigned*)ib, (unsigned*)Wlb, (unsigned*)Wrb00,
      Wrc, (unsigned*)Wrcb, bc, (unsigned*)xu1b, (unsigned*)xi1b,
      dst_buys, dst_rev, dst_fol, cntBB);
  k_scan<<<NSCANB, 256, 0, stream>>>(cntBB, sscan);
  k_pfill<<<NBLK, 256, 0, stream>>>(
      src_buys, dst_buys, src_rev, dst_rev, src_fol, dst_fol, sscan, binned);
  k_csr<<<NBUCK, 256, 0, stream>>>(binned, sscan, cnt, offs, esrc);

  // FUSED layer-1: gather-mean + MFMA GEMM + LN + ReLU (no meanL1b round-trip)
  k_l1<<<GRID_I + GRID_U, 256, 0, stream>>>(offs, cnt, esrc,
      (const uint4*)ub, (const uint4*)ib, Wlb, Wrb00, Wrcb,
      bl + 0 * NH, ln_g + 1 * NH, ln_b + 1 * NH, xi1b,
      bc, ln_g + 0 * NH, ln_b + 0 * NH, xu1b);

  // layer-2 aggregation at targets only (item update is dead code)
  k_agg_tgt<<<AGGT_G * 8, 256, 0, stream>>>(
      tgt, offs, cnt, esrc, (const uint4*)xu1b, (const uint4*)xi1b,
      mrev2, mfol2, xsel2);

  // layer-2 user GEMM/LN + final MLP fused (h2 stays in LDS)
  k_gemm_mlp<<<NTGT / 64, 256, 0, stream>>>(
      mrev2, Wl + (1 * 3 + 1) * NHNH,
      mfol2, Wl + (1 * 3 + 2) * NHNH,
      xsel2, Wrc + NHNH,
      bc + NH, ln_g + 2 * NH, ln_b + 2 * NH,
      W1, b1, W2, b2, outp, NTGT);
}

// Round 7
// 413.082 us; speedup vs baseline: 1.2867x; 1.2867x over previous
//
#include <hip/hip_runtime.h>

#define N_USERS 100000
#define N_ITEMS 50000
#define NEDGE   800000
#define NH      128
#define NHNH    16384
#define NTGT    8192
#define NNODE   250000      // 50K item slots (buys) + 100K user (rev) + 100K user (fol)
#define BASE_REV 50000
#define BASE_FOL 150000
#define NBUCK   588         // 196 buys (256 nodes) + 196 rev (512) + 196 fol (512)
#define NBLK    384         // binning blocks
#define NPB     6250        // edges per binning block: 384*6250 = 2400000 exactly
#define NRUN    (NBUCK * NBLK)        // 225792 per-(bucket,block) runs
#define NSCANB  441                   // 225792 / 512 exactly
#define PADCAP  4096        // per-bucket esrc slack for 8-padding (max 512*7+7=3591)
#define GRID_I  391         // (N_ITEMS+127)/128
#define GRID_U  782         // (N_USERS+127)/128
#define NPREP   9449        // prep blocks inside k_prep_count
#define AGG1_G  1954        // ceil(NNODE / 128); k_agg1 grid = AGG1_G*8
#define AGGT_G  128         // 2*NTGT units / 128; k_agg_tgt grid = AGGT_G*8
#define NCLR    62          // flag-clear blocks in prep (250368 B / 16 / 256)
#define NMARK   782         // edge-scan mark blocks in k_pfill (1.6M / 2048)
#define NCPT    587         // compaction blocks in k_csr (196 items + 391 users)
#define NI_PAD  50176       // 196*256
#define NU_PAD  100096      // 391*256

typedef __attribute__((ext_vector_type(8))) short short8;
typedef __attribute__((ext_vector_type(4))) float f32x4;
typedef __attribute__((ext_vector_type(2))) float f32x2;

// ---------------------------------------------------------------- bf16 helpers (RNE, manual)
__device__ __forceinline__ unsigned rne_hi(float f) {
  unsigned u = __float_as_uint(f);
  u += 0x7FFFu + ((u >> 16) & 1u);
  return u & 0xFFFF0000u;
}
__device__ __forceinline__ unsigned pack2(float f0, float f1) {
  return (rne_hi(f0) >> 16) | rne_hi(f1);   // low ushort = f0, high = f1
}
__device__ __forceinline__ float blo(unsigned u) { return __uint_as_float(u << 16); }
__device__ __forceinline__ float bhi(unsigned u) { return __uint_as_float(u & 0xFFFF0000u); }

__device__ __forceinline__ int bucket_of(int n) {
  return (n < BASE_REV) ? (n >> 8)
       : (n < BASE_FOL) ? 196 + ((n - BASE_REV) >> 9)
                        : 392 + ((n - BASE_FOL) >> 9);
}

// W fragment-order permutation: output 16B chunk c (of 2048 per matrix) holds
// floats [fs, fs+8) so the GEMM's b[j] load (chunk (kcb*8+j)*64 + lane) is a
// fully coalesced 1KB wave read.
__device__ __forceinline__ int wperm_src(int c) {
  int lane = c & 63, j = (c >> 6) & 7, kc8 = c >> 9;
  return (16 * j + (lane & 15)) * 128 + kc8 * 32 + (lane >> 4) * 8;
}

// ---------------------------------------------------------------- fused prep + pass-A histogram + flag clear
// [0,6250) ub | [6250,9375) ib | [9375,9423) Wlb(perm) | [9423,9431) Wrb00 |
// [9431,9439) Wrc+Wrcb | [9439,9447) Wrc1 | 9447 bc | 9448 zero rows |
// [NPREP, NPREP+NBLK) histogram | [NPREP+NBLK, +NCLR) clear need-flags
__global__ __launch_bounds__(256) void k_prep_count(
    const float* __restrict__ eu, const float* __restrict__ ei,
    const float* __restrict__ Wl, const float* __restrict__ Wr,
    const float* __restrict__ bl,
    unsigned* __restrict__ ub, unsigned* __restrict__ ib,
    unsigned* __restrict__ Wlb, unsigned* __restrict__ Wrb00,
    float* __restrict__ Wrc, unsigned* __restrict__ Wrcb, float* __restrict__ bc,
    unsigned* __restrict__ xub, unsigned* __restrict__ xib,
    const int* __restrict__ db, const int* __restrict__ dr,
    const int* __restrict__ df, int* __restrict__ cntBB,
    uint4* __restrict__ flagsclr)
{
  __shared__ int h[NBUCK];
  int b = blockIdx.x, t = threadIdx.x;
  if (b < 9375) {
    const float* src; unsigned* dst; int i;
    if (b < 6250)      { src = eu; dst = ub;    i = b * 256 + t; }
    else               { src = ei; dst = ib;    i = (b - 6250) * 256 + t; }
    const float4* xp = (const float4*)src;
    float4 a = xp[(size_t)i * 2];
    float4 c = xp[(size_t)i * 2 + 1];
    ((uint4*)dst)[i] = make_uint4(pack2(a.x, a.y), pack2(a.z, a.w),
                                  pack2(c.x, c.y), pack2(c.z, c.w));
  } else if (b < 9423) {
    int i = (b - 9375) * 256 + t;          // [0, 12288)
    int m = i >> 11, c = i & 2047;
    const float4* p = (const float4*)(Wl + m * NHNH + wperm_src(c));
    float4 a = p[0], cc = p[1];
    ((uint4*)Wlb)[i] = make_uint4(pack2(a.x, a.y), pack2(a.z, a.w),
                                  pack2(cc.x, cc.y), pack2(cc.z, cc.w));
  } else if (b < 9431) {
    int i = (b - 9423) * 256 + t;          // [0, 2048)
    const float4* p = (const float4*)(Wr + wperm_src(i));
    float4 a = p[0], cc = p[1];
    ((uint4*)Wrb00)[i] = make_uint4(pack2(a.x, a.y), pack2(a.z, a.w),
                                    pack2(cc.x, cc.y), pack2(cc.z, cc.w));
  } else if (b < 9439) {
    int i = (b - 9431) * 256 + t;          // [0, 2048)
    const float4* w1 = (const float4*)(Wr + 1 * NHNH);
    const float4* w2 = (const float4*)(Wr + 2 * NHNH);
    float4 a1 = w1[(size_t)i * 2],     a2 = w2[(size_t)i * 2];
    float4 c1 = w1[(size_t)i * 2 + 1], c2 = w2[(size_t)i * 2 + 1];
    ((float4*)Wrc)[(size_t)i * 2] =
        make_float4(a1.x + a2.x, a1.y + a2.y, a1.z + a2.z, a1.w + a2.w);
    ((float4*)Wrc)[(size_t)i * 2 + 1] =
        make_float4(c1.x + c2.x, c1.y + c2.y, c1.z + c2.z, c1.w + c2.w);
    int fs = wperm_src(i);
    const float4* p1 = (const float4*)(Wr + 1 * NHNH + fs);
    const float4* p2 = (const float4*)(Wr + 2 * NHNH + fs);
    float4 pa = p1[0], pc = p1[1], qa = p2[0], qc = p2[1];
    float4 sa = make_float4(pa.x + qa.x, pa.y + qa.y, pa.z + qa.z, pa.w + qa.w);
    float4 sc = make_float4(pc.x + qc.x, pc.y + qc.y, pc.z + qc.z, pc.w + qc.w);
    ((uint4*)Wrcb)[i] = make_uint4(pack2(sa.x, sa.y), pack2(sa.z, sa.w),
                                   pack2(sc.x, sc.y), pack2(sc.z, sc.w));
  } else if (b < 9447) {
    int i = (b - 9439) * 256 + t;
    const float4* w1 = (const float4*)(Wr + 4 * NHNH);
    const float4* w2 = (const float4*)(Wr + 5 * NHNH);
    float4 a1 = w1[(size_t)i * 2],     a2 = w2[(size_t)i * 2];
    float4 c1 = w1[(size_t)i * 2 + 1], c2 = w2[(size_t)i * 2 + 1];
    ((float4*)(Wrc + NHNH))[(size_t)i * 2] =
        make_float4(a1.x + a2.x, a1.y + a2.y, a1.z + a2.z, a1.w + a2.w);
    ((float4*)(Wrc + NHNH))[(size_t)i * 2 + 1] =
        make_float4(c1.x + c2.x, c1.y + c2.y, c1.z + c2.z, c1.w + c2.w);
  } else if (b == 9447) {
    if (t < NH)       bc[t]      = bl[1 * NH + t] + bl[2 * NH + t];
    else if (t < 2*NH) { int r = t - NH; bc[NH + r] = bl[4 * NH + r] + bl[5 * NH + r]; }
  } else if (b == 9448) {
    if (t < 64) {
      int row = t >> 4, q = t & 15;
      uint4 z = make_uint4(0u, 0u, 0u, 0u);
      uint4* p = (row == 0) ? (uint4*)ub  + (size_t)N_USERS * 16
               : (row == 1) ? (uint4*)ib  + (size_t)N_ITEMS * 16
               : (row == 2) ? (uint4*)xub + (size_t)N_USERS * 16
                            : (uint4*)xib + (size_t)N_ITEMS * 16;
      p[q] = z;
    }
  } else if (b < NPREP + NBLK) {
    // ---- pass A histogram, blk = b - NPREP
    int blk = b - NPREP;
    for (int j = t; j < NBUCK; j += 256) h[j] = 0;
    __syncthreads();
    int ebase = blk * NPB;
    for (int i = t; i < NPB; i += 256) {
      int e = ebase + i, n;
      if (e < NEDGE)          n = db[e];
      else if (e < 2 * NEDGE) n = BASE_REV + dr[e - NEDGE];
      else                    n = BASE_FOL + df[e - 2 * NEDGE];
      atomicAdd(&h[bucket_of(n)], 1);
    }
    __syncthreads();
    for (int j = t; j < NBUCK; j += 256) cntBB[j * NBLK + blk] = h[j];
  } else {
    // ---- clear is_tgt + need_u + need_i (contiguous 250368 B = 15648 uint4)
    int i = (b - NPREP - NBLK) * 256 + t;
    if (i < 15648) flagsclr[i] = make_uint4(0u, 0u, 0u, 0u);
  }
}

// ---------------------------------------------------------------- scan + target-mark blocks
__global__ __launch_bounds__(256) void k_scan(const int* __restrict__ cntBB,
                                              int* __restrict__ sscan,
                                              const int* __restrict__ tg,
                                              unsigned char* __restrict__ is_tgt,
                                              unsigned char* __restrict__ need_u)
{
  int t = threadIdx.x, blk = blockIdx.x;
  if (blk >= NSCANB) {
    int i = (blk - NSCANB) * 256 + t;     // NTGT = 32*256 exact
    int u = tg[i];
    is_tgt[u] = 1;
    need_u[u] = 1;                        // xsel needs xu1b[target]
    return;
  }
  int base = blk * 512;
  int lane = t & 63, w = t >> 6;
  int Ps = 0;
  for (int i = t * 4; i + 3 < base; i += 1024) {
    int4 v = *(const int4*)&cntBB[i];
    Ps += v.x + v.y + v.z + v.w;
  }
  #pragma unroll
  for (int o = 32; o > 0; o >>= 1) Ps += __shfl_xor(Ps, o);
  __shared__ int red[4];
  if (lane == 0) red[w] = Ps;
  __syncthreads();
  int P = red[0] + red[1] + red[2] + red[3];
  int a0 = cntBB[base + t * 2], a1 = cntBB[base + t * 2 + 1];
  int sum = a0 + a1;
  int v = sum;
  #pragma unroll
  for (int o = 1; o < 64; o <<= 1) { int u = __shfl_up(v, o); if (lane >= o) v += u; }
  __shared__ int wsum[4];
  if (lane == 63) wsum[w] = v;
  __syncthreads();
  int wb = 0;
  for (int i = 0; i < w; ++i) wb += wsum[i];
  int excl = wb + v - sum;
  sscan[base + t * 2]     = P + excl;
  sscan[base + t * 2 + 1] = P + excl + a0;
  if (blk == NSCANB - 1 && t == 255)
    sscan[NRUN] = P + wsum[0] + wsum[1] + wsum[2] + wsum[3];   // == 3*NEDGE
}

// ---------------------------------------------------------------- pass B scatter + edge-scan mark blocks
__global__ __launch_bounds__(256) void k_pfill(
    const int* __restrict__ sb, const int* __restrict__ db,
    const int* __restrict__ sr, const int* __restrict__ dr,
    const int* __restrict__ sf, const int* __restrict__ df,
    const int* __restrict__ sscan, int* __restrict__ binned,
    const unsigned char* __restrict__ is_tgt,
    unsigned char* __restrict__ need_u, unsigned char* __restrict__ need_i)
{
  __shared__ int cur[NBUCK];
  int t = threadIdx.x, blk = blockIdx.x;
  if (blk >= NBLK) {
    // mark needed sources: items via rev edges into targets, users via fol edges
    int eb = (blk - NBLK) * 2048;
    #pragma unroll
    for (int k2 = 0; k2 < 8; ++k2) {
      int e = eb + k2 * 256 + t;
      if (e < NEDGE)            { if (is_tgt[dr[e]]) need_i[sr[e]] = 1; }
      else if (e < 2 * NEDGE)   { int e2 = e - NEDGE; if (is_tgt[df[e2]]) need_u[sf[e2]] = 1; }
    }
    return;
  }
  for (int j = t; j < NBUCK; j += 256) cur[j] = sscan[j * NBLK + blk];
  __syncthreads();
  int ebase = blk * NPB;
  for (int i = t; i < NPB; i += 256) {
    int e = ebase + i, n, s;
    if (e < NEDGE)          { n = db[e];                      s = sb[e]; }
    else if (e < 2 * NEDGE) { n = BASE_REV + dr[e - NEDGE];   s = sr[e - NEDGE]; }
    else                    { n = BASE_FOL + df[e - 2*NEDGE]; s = sf[e - 2*NEDGE]; }
    int b = bucket_of(n);
    int local = (n < BASE_REV) ? (n & 255)
              : (n < BASE_FOL) ? ((n - BASE_REV) & 511)
                               : ((n - BASE_FOL) & 511);
    int pos = atomicAdd(&cur[b], 1);
    binned[pos] = (local << 17) | s;
  }
}

// ---------------------------------------------------------------- pass C: padded CSR build + flag compaction blocks
__global__ __launch_bounds__(256) void k_csr(
    const int* __restrict__ binned, const int* __restrict__ sscan,
    int* __restrict__ cnt, int* __restrict__ offs, int* __restrict__ esrc,
    const unsigned char* __restrict__ need_i,
    const unsigned char* __restrict__ need_u,
    int* __restrict__ list_i, int* __restrict__ list_u, int* __restrict__ cnt2)
{
  __shared__ int h[512], fl[512];
  __shared__ int wsum[4];
  int t = threadIdx.x, b = blockIdx.x;
  int lane = t & 63, w = t >> 6;

  if (b >= NBUCK) {
    // ---- compact needed flags into row lists (brute global prefix, popcount)
    int cb = b - NBUCK;
    const unsigned char* flags; int Nv; int* list; int lo; int isLast; int which;
    if (cb < 196) { flags = need_i; Nv = N_ITEMS; list = list_i; lo = cb * 256;        isLast = (cb == 195); which = 0; }
    else          { flags = need_u; Nv = N_USERS; list = list_u; lo = (cb - 196) * 256; isLast = (cb == NCPT - 1); which = 1; }
    int nw = lo >> 2;
    const unsigned* wf = (const unsigned*)flags;
    int s = 0;
    for (int i = t; i < nw; i += 256) s += __builtin_popcount(wf[i]);
    #pragma unroll
    for (int o = 32; o > 0; o >>= 1) s += __shfl_xor(s, o);
    if (lane == 0) wsum[w] = s;
    __syncthreads();
    int base = wsum[0] + wsum[1] + wsum[2] + wsum[3];
    __syncthreads();
    int idx = lo + t;
    int f = (idx < Nv) ? (int)flags[idx] : 0;
    int v = f;
    #pragma unroll
    for (int o = 1; o < 64; o <<= 1) { int u2 = __shfl_up(v, o); if (lane >= o) v += u2; }
    if (lane == 63) wsum[w] = v;
    __syncthreads();
    int wb = 0;
    for (int i = 0; i < w; ++i) wb += wsum[i];
    int excl = base + wb + (v - f);
    if (f) list[excl] = idx;
    if (isLast && t == 255)
      cnt2[which] = base + wsum[0] + wsum[1] + wsum[2] + wsum[3];
    return;
  }

  int n0, S, zpad;
  if (b < 196)      { n0 = b * 256;                    S = min(256, BASE_REV - n0); zpad = N_USERS; }
  else if (b < 392) { n0 = BASE_REV + (b - 196) * 512; S = min(512, BASE_FOL - n0); zpad = N_ITEMS; }
  else              { n0 = BASE_FOL + (b - 392) * 512; S = min(512, NNODE - n0);    zpad = N_USERS; }
  int e0 = sscan[b * NBLK];
  int e1 = sscan[(b + 1) * NBLK];
  int e0p = ((e0 + 7) & ~7) + b * PADCAP;   // 8-aligned padded region base
  h[t] = 0; h[t + 256] = 0;
  __syncthreads();
  for (int e = e0 + t; e < e1; e += 256)
    atomicAdd(&h[binned[e] >> 17], 1);
  __syncthreads();
  int a0 = h[t * 2], a1 = h[t * 2 + 1];
  int p0 = (a0 + 7) & ~7, p1 = (a1 + 7) & ~7;   // padded counts (0 stays 0)
  int v = p0 + p1;
  #pragma unroll
  for (int o = 1; o < 64; o <<= 1) { int u = __shfl_up(v, o); if (lane >= o) v += u; }
  if (lane == 63) wsum[w] = v;
  __syncthreads();
  int wb = 0;
  for (int i = 0; i < w; ++i) wb += wsum[i];
  int excl = wb + v - (p0 + p1);
  int ps0 = e0p + excl, ps1 = e0p + excl + p0;
  fl[t * 2]     = ps0;
  fl[t * 2 + 1] = ps1;
  if (t * 2 < S)     { cnt[n0 + t * 2]     = a0; offs[n0 + t * 2]     = ps0; }
  if (t * 2 + 1 < S) { cnt[n0 + t * 2 + 1] = a1; offs[n0 + t * 2 + 1] = ps1; }
  __syncthreads();
  for (int e = e0 + t; e < e1; e += 256) {
    int v2 = binned[e];
    int p = atomicAdd(&fl[v2 >> 17], 1);
    esrc[p] = v2 & 0x1FFFF;
  }
  __syncthreads();
  for (int e = ps0 + a0; e < ps0 + p0; ++e) esrc[e] = zpad;
  for (int e = ps1 + a1; e < ps1 + p1; ++e) esrc[e] = zpad;
}

// ---------------------------------------------------------------- layer-1 mean aggregation (XCD feature-split + dead-node skip)
__global__ __launch_bounds__(256) void k_agg1(
    const int* __restrict__ offs, const int* __restrict__ cnt,
    const int* __restrict__ esrc,
    const uint4* __restrict__ ub4, const uint4* __restrict__ ib4,
    uint4* __restrict__ mean4,
    const unsigned char* __restrict__ need_i,
    const unsigned char* __restrict__ need_u)
{
  int bid = blockIdx.x;
  int x = bid & 7, g = bid >> 3;
  int half = x >> 2, sub = x & 3;
  int sid = threadIdx.x >> 3, ln = threadIdx.x & 7;
  int n = (g * 4 + sub) * 32 + sid;
  if (n >= NNODE) return;
  // dead-node elimination: layer-2 never reads this slot's layer-1 output
  int flagv;
  if (n < BASE_REV)      flagv = need_i[n];
  else if (n < BASE_FOL) flagv = need_u[n - BASE_REV];
  else                   flagv = need_u[n - BASE_FOL];
  if (!flagv) return;
  int sl = half * 8 + ln;
  const uint4* table = (n < BASE_REV) ? ub4 : (n < BASE_FOL) ? ib4 : ub4;
  int st = offs[n], c = cnt[n];
  int nch = (c + 7) >> 3;
  f32x2 a0 = {0.f, 0.f}, a1 = {0.f, 0.f}, a2 = {0.f, 0.f}, a3 = {0.f, 0.f};
  for (int ch = 0; ch < nch; ++ch) {
    int4 sA = *(const int4*)&esrc[st + ch * 8];
    int4 sB = *(const int4*)&esrc[st + ch * 8 + 4];
    uint4 v0 = table[(size_t)sA.x * 16 + sl];
    uint4 v1 = table[(size_t)sA.y * 16 + sl];
    uint4 v2 = table[(size_t)sA.z * 16 + sl];
    uint4 v3 = table[(size_t)sA.w * 16 + sl];
    uint4 v4 = table[(size_t)sB.x * 16 + sl];
    uint4 v5 = table[(size_t)sB.y * 16 + sl];
    uint4 v6 = table[(size_t)sB.z * 16 + sl];
    uint4 v7 = table[(size_t)sB.w * 16 + sl];
    a0 += (f32x2){blo(v0.x), bhi(v0.x)} + (f32x2){blo(v1.x), bhi(v1.x)}
        + (f32x2){blo(v2.x), bhi(v2.x)} + (f32x2){blo(v3.x), bhi(v3.x)}
        + (f32x2){blo(v4.x), bhi(v4.x)} + (f32x2){blo(v5.x), bhi(v5.x)}
        + (f32x2){blo(v6.x), bhi(v6.x)} + (f32x2){blo(v7.x), bhi(v7.x)};
    a1 += (f32x2){blo(v0.y), bhi(v0.y)} + (f32x2){blo(v1.y), bhi(v1.y)}
        + (f32x2){blo(v2.y), bhi(v2.y)} + (f32x2){blo(v3.y), bhi(v3.y)}
        + (f32x2){blo(v4.y), bhi(v4.y)} + (f32x2){blo(v5.y), bhi(v5.y)}
        + (f32x2){blo(v6.y), bhi(v6.y)} + (f32x2){blo(v7.y), bhi(v7.y)};
    a2 += (f32x2){blo(v0.z), bhi(v0.z)} + (f32x2){blo(v1.z), bhi(v1.z)}
        + (f32x2){blo(v2.z), bhi(v2.z)} + (f32x2){blo(v3.z), bhi(v3.z)}
        + (f32x2){blo(v4.z), bhi(v4.z)} + (f32x2){blo(v5.z), bhi(v5.z)}
        + (f32x2){blo(v6.z), bhi(v6.z)} + (f32x2){blo(v7.z), bhi(v7.z)};
    a3 += (f32x2){blo(v0.w), bhi(v0.w)} + (f32x2){blo(v1.w), bhi(v1.w)}
        + (f32x2){blo(v2.w), bhi(v2.w)} + (f32x2){blo(v3.w), bhi(v3.w)}
        + (f32x2){blo(v4.w), bhi(v4.w)} + (f32x2){blo(v5.w), bhi(v5.w)}
        + (f32x2){blo(v6.w), bhi(v6.w)} + (f32x2){blo(v7.w), bhi(v7.w)};
  }
  float inv = 1.0f / fmaxf((float)c, 1.0f);
  mean4[(size_t)n * 16 + sl] =
      make_uint4(pack2(a0.x * inv, a0.y * inv), pack2(a1.x * inv, a1.y * inv),
                 pack2(a2.x * inv, a2.y * inv), pack2(a3.x * inv, a3.y * inv));
}

// ---------------------------------------------------------------- layer-2 target aggregation (XCD feature-split)
__global__ __launch_bounds__(256) void k_agg_tgt(
    const int* __restrict__ tgt, const int* __restrict__ offs,
    const int* __restrict__ cnt, const int* __restrict__ esrc,
    const uint4* __restrict__ xu1b4, const uint4* __restrict__ xi1b4,
    float* __restrict__ mrev, float* __restrict__ mfol, float* __restrict__ xsel)
{
  int bid = blockIdx.x;
  int x = bid & 7, g = bid >> 3;
  int half = x >> 2, sub = x & 3;
  int sid = threadIdx.x >> 3, ln = threadIdx.x & 7;
  int unit = (g * 4 + sub) * 32 + sid;   // [0, 2*NTGT)
  int tg = unit >> 1, which = unit & 1;
  int u = tgt[tg];
  int n = (which ? BASE_FOL : BASE_REV) + u;
  const uint4* table = which ? xu1b4 : xi1b4;
  int sl = half * 8 + ln;
  int st = offs[n], c = cnt[n];
  int nch = (c + 7) >> 3;
  f32x2 a0 = {0.f, 0.f}, a1 = {0.f, 0.f}, a2 = {0.f, 0.f}, a3 = {0.f, 0.f};
  for (int ch = 0; ch < nch; ++ch) {
    int4 sA = *(const int4*)&esrc[st + ch * 8];
    int4 sB = *(const int4*)&esrc[st + ch * 8 + 4];
    uint4 v0 = table[(size_t)sA.x * 16 + sl];
    uint4 v1 = table[(size_t)sA.y * 16 + sl];
    uint4 v2 = table[(size_t)sA.z * 16 + sl];
    uint4 v3 = table[(size_t)sA.w * 16 + sl];
    uint4 v4 = table[(size_t)sB.x * 16 + sl];
    uint4 v5 = table[(size_t)sB.y * 16 + sl];
    uint4 v6 = table[(size_t)sB.z * 16 + sl];
    uint4 v7 = table[(size_t)sB.w * 16 + sl];
    a0 += (f32x2){blo(v0.x), bhi(v0.x)} + (f32x2){blo(v1.x), bhi(v1.x)}
        + (f32x2){blo(v2.x), bhi(v2.x)} + (f32x2){blo(v3.x), bhi(v3.x)}
        + (f32x2){blo(v4.x), bhi(v4.x)} + (f32x2){blo(v5.x), bhi(v5.x)}
        + (f32x2){blo(v6.x), bhi(v6.x)} + (f32x2){blo(v7.x), bhi(v7.x)};
    a1 += (f32x2){blo(v0.y), bhi(v0.y)} + (f32x2){blo(v1.y), bhi(v1.y)}
        + (f32x2){blo(v2.y), bhi(v2.y)} + (f32x2){blo(v3.y), bhi(v3.y)}
        + (f32x2){blo(v4.y), bhi(v4.y)} + (f32x2){blo(v5.y), bhi(v5.y)}
        + (f32x2){blo(v6.y), bhi(v6.y)} + (f32x2){blo(v7.y), bhi(v7.y)};
    a2 += (f32x2){blo(v0.z), bhi(v0.z)} + (f32x2){blo(v1.z), bhi(v1.z)}
        + (f32x2){blo(v2.z), bhi(v2.z)} + (f32x2){blo(v3.z), bhi(v3.z)}
        + (f32x2){blo(v4.z), bhi(v4.z)} + (f32x2){blo(v5.z), bhi(v5.z)}
        + (f32x2){blo(v6.z), bhi(v6.z)} + (f32x2){blo(v7.z), bhi(v7.z)};
    a3 += (f32x2){blo(v0.w), bhi(v0.w)} + (f32x2){blo(v1.w), bhi(v1.w)}
        + (f32x2){blo(v2.w), bhi(v2.w)} + (f32x2){blo(v3.w), bhi(v3.w)}
        + (f32x2){blo(v4.w), bhi(v4.w)} + (f32x2){blo(v5.w), bhi(v5.w)}
        + (f32x2){blo(v6.w), bhi(v6.w)} + (f32x2){blo(v7.w), bhi(v7.w)};
  }
  float inv = 1.0f / fmaxf((float)c, 1.0f);
  float4 o0 = make_float4(a0.x * inv, a0.y * inv, a1.x * inv, a1.y * inv);
  float4 o1 = make_float4(a2.x * inv, a2.y * inv, a3.x * inv, a3.y * inv);
  float* outp = which ? mfol : mrev;
  ((float4*)outp)[(size_t)tg * 32 + sl * 2]     = o0;
  ((float4*)outp)[(size_t)tg * 32 + sl * 2 + 1] = o1;
  if (!which) {
    uint4 xv = xu1b4[(size_t)u * 16 + sl];
    ((float4*)xsel)[(size_t)tg * 32 + sl * 2] =
        make_float4(blo(xv.x), bhi(xv.x), blo(xv.y), bhi(xv.y));
    ((float4*)xsel)[(size_t)tg * 32 + sl * 2 + 1] =
        make_float4(blo(xv.z), bhi(xv.z), blo(xv.w), bhi(xv.w));
  }
}

// ---------------------------------------------------------------- MFMA layer-1 GEMM on COMPACT row lists
// A staged per-wave via global_load_lds width-16 (linear LDS dest, per-lane
// swizzled global src: chunk ^= row&7; swizzled ds_read). W pre-permuted.
__device__ __forceinline__ void stage_tile_l(const unsigned short* __restrict__ Ag,
                                             const int* rid,
                                             unsigned short* As_w, int quad, int c0)
{
  #pragma unroll
  for (int r = 0; r < 8; ++r) {
    int swz = c0 ^ (4 * (r & 1) + quad);       // chunk ^ (row&7)
    const unsigned short* g = Ag + (size_t)rid[r] * NH + (swz << 3);
    __builtin_amdgcn_global_load_lds(
        (const __attribute__((address_space(1))) void*)g,
        (__attribute__((address_space(3))) void*)(As_w + r * 512),
        16, 0, 0);
  }
}

__device__ __forceinline__ void mfma_ln_body(
    int bx, const int* __restrict__ list, int cv,
    const unsigned short* __restrict__ A0, const unsigned short* __restrict__ W0,
    const unsigned short* __restrict__ A1, const unsigned short* __restrict__ W1,
    const unsigned short* __restrict__ A2, const unsigned short* __restrict__ W2,
    const float* __restrict__ bias, const float* __restrict__ lng,
    const float* __restrict__ lnb, unsigned short* __restrict__ out,
    unsigned short* smem)
{
  const int t = threadIdx.x;
  const int wv = t >> 6, lane = t & 63;
  const int quad = lane >> 4, c0 = lane & 15;
  unsigned short* As_w = smem + wv * 4096;
  const int m0 = bx * 128;

  int rid[8];
  #pragma unroll
  for (int r = 0; r < 8; ++r) {
    int m = m0 + wv * 32 + r * 4 + quad;
    rid[r] = list[min(m, cv - 1)];
  }

  f32x4 acc[2][8];
  #pragma unroll
  for (int i = 0; i < 2; ++i)
    #pragma unroll
    for (int j = 0; j < 8; ++j) acc[i][j] = (f32x4){0.f, 0.f, 0.f, 0.f};

  stage_tile_l(A0, rid, As_w, quad, c0);

  const int xr = c0 & 7;
  #pragma unroll
  for (int term = 0; term < 3; ++term) {
    const unsigned short* A = (term == 0) ? A0 : (term == 1) ? A1 : A2;
    if (!A) continue;
    const unsigned short* W = (term == 0) ? W0 : (term == 1) ? W1 : W2;
    asm volatile("s_waitcnt vmcnt(0)" ::: "memory");
    __builtin_amdgcn_sched_barrier(0);
    #pragma unroll
    for (int kcb = 0; kcb < 4; ++kcb) {
      short8 b[8];
      #pragma unroll
      for (int j = 0; j < 8; ++j)
        b[j] = *(const short8*)(W + (((kcb * 8 + j) << 6) + lane) * 8);
      int cg = (kcb << 2) + quad;
      short8 a0 = *(const short8*)(As_w + c0 * 128        + ((cg ^ xr) << 3));
      short8 a1 = *(const short8*)(As_w + (c0 + 16) * 128 + ((cg ^ xr) << 3));
      #pragma unroll
      for (int j = 0; j < 8; ++j) {
        acc[0][j] = __builtin_amdgcn_mfma_f32_16x16x32_bf16(a0, b[j], acc[0][j], 0, 0, 0);
        acc[1][j] = __builtin_amdgcn_mfma_f32_16x16x32_bf16(a1, b[j], acc[1][j], 0, 0, 0);
      }
    }
    const unsigned short* An = (term == 0) ? A1 : (term == 1) ? A2 : nullptr;
    if (An) {
      asm volatile("s_waitcnt lgkmcnt(0)" ::: "memory");   // ds_reads drained before DMA overwrite
      __builtin_amdgcn_sched_barrier(0);
      stage_tile_l(An, rid, As_w, quad, c0);
    }
  }

  __syncthreads();   // all waves done reading stage regions (ytile aliases them)

  float bb[8], gg[8], ll[8];
  #pragma unroll
  for (int j = 0; j < 8; ++j) {
    bb[j] = bias[16 * j + c0]; gg[j] = lng[16 * j + c0]; ll[j] = lnb[16 * j + c0];
  }

  unsigned short* yt = smem + wv * 4224;       // ytile[wv][32][132]
  #pragma unroll
  for (int i = 0; i < 2; ++i) {
    #pragma unroll
    for (int r = 0; r < 4; ++r) {
      float v[8]; float s = 0.f, ss = 0.f;
      #pragma unroll
      for (int j = 0; j < 8; ++j) {
        float x = acc[i][j][r] + bb[j];
        v[j] = x; s += x; ss += x * x;
      }
      #pragma unroll
      for (int o = 1; o < 16; o <<= 1) { s += __shfl_xor(s, o); ss += __shfl_xor(ss, o); }
      float mu = s * (1.0f / 128.0f);
      float var = ss * (1.0f / 128.0f) - mu * mu;
      float rinv = rsqrtf(var + 1e-5f);
      int rl = 16 * i + quad * 4 + r;
      #pragma unroll
      for (int j = 0; j < 8; ++j) {
        float y = fmaxf((v[j] - mu) * rinv * gg[j] + ll[j], 0.f);
        yt[rl * 132 + 16 * j + c0] = (unsigned short)(rne_hi(y) >> 16);
      }
    }
  }
  __syncthreads();
  #pragma unroll
  for (int it = 0; it < 16; ++it) {
    int idx = it * 256 + t;
    int row = idx >> 5, c4 = (idx & 31) * 4;
    int node = list[min(m0 + row, cv - 1)];
    *(uint2*)(out + (size_t)node * NH + c4) =
        *(const uint2*)(smem + (row >> 5) * 4224 + (row & 31) * 132 + c4);
  }
}

// merged launch: blocks [0,GRID_I) item GEMM, [GRID_I, GRID_I+GRID_U) user GEMM
__global__ __launch_bounds__(256) void k_mfma_ln2(
    const int* __restrict__ list_i, const int* __restrict__ list_u,
    const int* __restrict__ cnt2,
    const unsigned short* __restrict__ meanb,
    const unsigned short* __restrict__ ib, const unsigned short* __restrict__ ub,
    const unsigned short* __restrict__ Wlb,
    const unsigned short* __restrict__ Wrb00,
    const unsigned short* __restrict__ Wrcb,
    const float* __restrict__ ibias, const float* __restrict__ ilng,
    const float* __restrict__ ilnb, unsigned short* __restrict__ xi1b,
    const float* __restrict__ ubias, const float* __restrict__ ulng,
    const float* __restrict__ ulnb, unsigned short* __restrict__ xu1b)
{
  __shared__ unsigned short smem[16896];       // 33792 B: stage (32KB) + ytile reuse
  int b = blockIdx.x;
  if (b < GRID_I) {
    int cv = cnt2[0];
    if (b * 128 >= cv) return;
    mfma_ln_body(b, list_i, cv,
                 meanb, Wlb + 0 * NHNH, ib, Wrb00, nullptr, nullptr,
                 ibias, ilng, ilnb, xi1b, smem);
  } else {
    int cv = cnt2[1];
    int b2 = b - GRID_I;
    if (b2 * 128 >= cv) return;
    mfma_ln_body(b2, list_u, cv,
                 meanb + (size_t)BASE_REV * NH, Wlb + 1 * NHNH,
                 meanb + (size_t)BASE_FOL * NH, Wlb + 2 * NHNH,
                 ub, Wrcb,
                 ubias, ulng, ulnb, xu1b, smem);
  }
}

// ---------------------------------------------------------------- fp32 GEMM + bias + LN + ReLU + fused final MLP
__global__ __launch_bounds__(256) void k_gemm_mlp(
    const float* __restrict__ A0, const float* __restrict__ W0,
    const float* __restrict__ A1, const float* __restrict__ W1,
    const float* __restrict__ A2, const float* __restrict__ W2,
    const float* __restrict__ bias, const float* __restrict__ lng,
    const float* __restrict__ lnb,
    const float* __restrict__ W1m, const float* __restrict__ b1m,
    const float* __restrict__ W2m, const float* __restrict__ b2m,
    float* __restrict__ out, int M)
{
  __shared__ float smem[12800];
  float* As  = smem;              // [32][68]
  float* Ws  = smem + 2176;       // [4224]
  float* hs  = smem;              // [64][132] (MLP phase)
  float* W1s = smem + 8448;       // [32][132]
  float* b1s = smem + 12672;      // [64]
  float* W2s = smem + 12736;      // [64]

  const int t = threadIdx.x;
  const int tx = t & 31, ty = t >> 5;
  const int rowbase = blockIdx.x * 64;

  float acc[8][4];
  #pragma unroll
  for (int i = 0; i < 8; ++i)
    #pragma unroll
    for (int j = 0; j < 4; ++j) acc[i][j] = 0.f;

  const int arow = t >> 2;
  const int ak8  = (t & 3) * 8;

  #pragma unroll
  for (int term = 0; term < 3; ++term) {
    const float* A = (term == 0) ? A0 : (term == 1) ? A1 : A2;
    const float* W = (term == 0) ? W0 : (term == 1) ? W1 : W2;
    if (A == nullptr) continue;
    for (int kc = 0; kc < NH; kc += 32) {
      {
        int gr = rowbase + arow; if (gr > M - 1) gr = M - 1;
        const float* ap = &A[(size_t)gr * NH + kc + ak8];
        float4 v0 = *(const float4*)(ap);
        float4 v1 = *(const float4*)(ap + 4);
        As[(ak8 + 0) * 68 + arow] = v0.x; As[(ak8 + 1) * 68 + arow] = v0.y;
        As[(ak8 + 2) * 68 + arow] = v0.z; As[(ak8 + 3) * 68 + arow] = v0.w;
        As[(ak8 + 4) * 68 + arow] = v1.x; As[(ak8 + 5) * 68 + arow] = v1.y;
        As[(ak8 + 6) * 68 + arow] = v1.z; As[(ak8 + 7) * 68 + arow] = v1.w;
      }
      #pragma unroll
      for (int i = 0; i < 4; ++i) {
        int linear = t * 4 + i * 1024;
        int j = linear >> 5, k4 = linear & 31;
        float4 v = *(const float4*)&W[j * NH + kc + k4];
        Ws[(k4 + 0) * 132 + j] = v.x; Ws[(k4 + 1) * 132 + j] = v.y;
        Ws[(k4 + 2) * 132 + j] = v.z; Ws[(k4 + 3) * 132 + j] = v.w;
      }
      __syncthreads();
      #pragma unroll
      for (int kk = 0; kk < 32; ++kk) {
        float4 alo = *(const float4*)&As[kk * 68 + ty * 8];
        float4 ahi = *(const float4*)&As[kk * 68 + ty * 8 + 4];
        float4 w4  = *(const float4*)&Ws[kk * 132 + tx * 4];
        float ar[8] = {alo.x, alo.y, alo.z, alo.w, ahi.x, ahi.y, ahi.z, ahi.w};
        float wr[4] = {w4.x, w4.y, w4.z, w4.w};
        #pragma unroll
        for (int i = 0; i < 8; ++i)
          #pragma unroll
          for (int j = 0; j < 4; ++j)
            acc[i][j] = fmaf(ar[i], wr[j], acc[i][j]);
      }
      __syncthreads();
    }
  }

  float4 b4 = *(const float4*)&bias[tx * 4];
  float4 g4 = *(const float4*)&lng[tx * 4];
  float4 l4 = *(const float4*)&lnb[tx * 4];
  float bb[4] = {b4.x, b4.y, b4.z, b4.w};
  float gg[4] = {g4.x, g4.y, g4.z, g4.w};
  float ll[4] = {l4.x, l4.y, l4.z, l4.w};

  #pragma unroll
  for (int i = 0; i < 8; ++i) {
    float s = 0.f, ss = 0.f;
    #pragma unroll
    for (int j = 0; j < 4; ++j) {
      float v = acc[i][j] + bb[j];
      acc[i][j] = v;
      s += v; ss += v * v;
    }
    #pragma unroll
    for (int o = 1; o < 32; o <<= 1) { s += __shfl_xor(s, o); ss += __shfl_xor(ss, o); }
    float mu = s * (1.0f / 128.0f);
    float var = ss * (1.0f / 128.0f) - mu * mu;
    float rinv = rsqrtf(var + 1e-5f);
    float* hp = &hs[(ty * 8 + i) * 132 + tx * 4];
    hp[0] = fmaxf((acc[i][0] - mu) * rinv * gg[0] + ll[0], 0.f);
    hp[1] = fmaxf((acc[i][1] - mu) * rinv * gg[1] + ll[1], 0.f);
    hp[2] = fmaxf((acc[i][2] - mu) * rinv * gg[2] + ll[2], 0.f);
    hp[3] = fmaxf((acc[i][3] - mu) * rinv * gg[3] + ll[3], 0.f);
  }
  if (t < 64) { b1s[t] = b1m[t]; W2s[t] = W2m[t]; }
  float b2v = b2m[0];

  int row = t >> 2, j = t & 3;
  float p = 0.f;
  #pragma unroll
  for (int half = 0; half < 2; ++half) {
    __syncthreads();
    #pragma unroll
    for (int i = 0; i < 16; ++i) {
      int idx = t + 256 * i;
      int j2 = idx >> 7, k2 = idx & 127;
      W1s[j2 * 132 + k2] = W1m[(half * 32 + j2) * 128 + k2];
    }
    __syncthreads();
    #pragma unroll
    for (int uu = 0; uu < 8; ++uu) {
      int ul = uu * 4 + j;
      float hacc = b1s[half * 32 + ul];
      const float* wrow = &W1s[ul * 132];
      const float* hrow = &hs[row * 132];
      #pragma unroll
      for (int k4 = 0; k4 < 32; ++k4) {
        float4 hv = *(const float4*)&hrow[k4 * 4];
        float4 wv = *(const float4*)&wrow[k4 * 4];
        hacc = fmaf(hv.x, wv.x, hacc);
        hacc = fmaf(hv.y, wv.y, hacc);
        hacc = fmaf(hv.z, wv.z, hacc);
        hacc = fmaf(hv.w, wv.w, hacc);
      }
      p += fmaxf(hacc, 0.f) * W2s[half * 32 + ul];
    }
  }
  p += __shfl_xor(p, 1);
  p += __shfl_xor(p, 2);
  if (j == 0) out[rowbase + row] = p + b2v;
}

// ---------------------------------------------------------------- launch
extern "C" void kernel_launch(void* const* d_in, const int* in_sizes, int n_in,
                              void* d_out, int out_size, void* d_ws, size_t ws_size,
                              hipStream_t stream)
{
  const float* emb_user = (const float*)d_in[0];
  const float* emb_item = (const float*)d_in[1];
  const float* Wl   = (const float*)d_in[2];   // [2,3,128,128]
  const float* bl   = (const float*)d_in[3];   // [2,3,128]
  const float* Wr   = (const float*)d_in[4];   // [2,3,128,128]
  const float* ln_g = (const float*)d_in[5];   // [2,2,128]
  const float* ln_b = (const float*)d_in[6];   // [2,2,128]
  const float* W1   = (const float*)d_in[7];   // [64,128]
  const float* b1   = (const float*)d_in[8];   // [64]
  const float* W2   = (const float*)d_in[9];   // [1,64]
  const float* b2   = (const float*)d_in[10];  // [1]
  const int* src_buys = (const int*)d_in[11];
  const int* dst_buys = (const int*)d_in[12];
  const int* src_rev  = (const int*)d_in[13];
  const int* dst_rev  = (const int*)d_in[14];
  const int* src_fol  = (const int*)d_in[15];
  const int* dst_fol  = (const int*)d_in[16];
  const int* tgt      = (const int*)d_in[17];
  float* outp = (float*)d_out;

  char* wp = (char*)d_ws;
  size_t ob = 0;
  auto take = [&](size_t bytes) -> void* {
    void* p = wp + ob;
    ob += (bytes + 255) & ~(size_t)255;
    return p;
  };
  int*            cnt     = (int*)           take((size_t)NNODE * 4);
  int*            offs    = (int*)           take((size_t)NNODE * 4);
  int*            cntBB   = (int*)           take((size_t)NRUN * 4);
  int*            sscan   = (int*)           take((size_t)(NRUN + 1) * 4);
  int*            esrc    = (int*)           take((size_t)(3 * NEDGE + (NBUCK + 1) * PADCAP) * 4);
  float*          Wrc     = (float*)         take((size_t)2 * NHNH * 4);
  float*          bc      = (float*)         take((size_t)2 * NH * 4);
  unsigned short* meanL1b = (unsigned short*)take((size_t)NNODE * NH * 2);
  // +1 zero pad row on each gather table (index N_USERS / N_ITEMS)
  unsigned short* ub      = (unsigned short*)take((size_t)(N_USERS + 1) * NH * 2);
  unsigned short* ib      = (unsigned short*)take((size_t)(N_ITEMS + 1) * NH * 2);
  unsigned short* xu1b    = (unsigned short*)take((size_t)(N_USERS + 1) * NH * 2);
  unsigned short* xi1b    = (unsigned short*)take((size_t)(N_ITEMS + 1) * NH * 2);
  unsigned short* Wlb     = (unsigned short*)take((size_t)6 * NHNH * 2);
  unsigned short* Wrb00   = (unsigned short*)take((size_t)NHNH * 2);
  unsigned short* Wrcb    = (unsigned short*)take((size_t)NHNH * 2);
  float*          mrev2   = (float*)         take((size_t)NTGT * NH * 4);
  float*          mfol2   = (float*)         take((size_t)NTGT * NH * 4);
  float*          xsel2   = (float*)         take((size_t)NTGT * NH * 4);
  // dead-node elimination state (is_tgt/need_u/need_i contiguous: sizes are
  // multiples of 256 so take() preserves contiguity for the single clear)
  unsigned char*  is_tgt  = (unsigned char*) take((size_t)NU_PAD);
  unsigned char*  need_u  = (unsigned char*) take((size_t)NU_PAD);
  unsigned char*  need_i  = (unsigned char*) take((size_t)NI_PAD);
  int*            list_i  = (int*)           take((size_t)NI_PAD * 4);
  int*            list_u  = (int*)           take((size_t)NU_PAD * 4);
  int*            cnt2    = (int*)           take(256);
  // binned edge buffer (9.6 MB) aliases meanL1b (64 MB): consumed by k_csr
  // before k_agg1 writes meanL1b.
  int*            binned  = (int*)meanL1b;

  k_prep_count<<<NPREP + NBLK + NCLR, 256, 0, stream>>>(emb_user, emb_item, Wl, Wr, bl,
      (unsigned*)ub, (unsigned*)ib, (unsigned*)Wlb, (unsigned*)Wrb00,
      Wrc, (unsigned*)Wrcb, bc, (unsigned*)xu1b, (unsigned*)xi1b,
      dst_buys, dst_rev, dst_fol, cntBB, (uint4*)is_tgt);
  k_scan<<<NSCANB + 32, 256, 0, stream>>>(cntBB, sscan, tgt, is_tgt, need_u);
  k_pfill<<<NBLK + NMARK, 256, 0, stream>>>(
      src_buys, dst_buys, src_rev, dst_rev, src_fol, dst_fol, sscan, binned,
      is_tgt, need_u, need_i);
  k_csr<<<NBUCK + NCPT, 256, 0, stream>>>(binned, sscan, cnt, offs, esrc,
      need_i, need_u, list_i, list_u, cnt2);
  k_agg1<<<AGG1_G * 8, 256, 0, stream>>>(offs, cnt, esrc,
      (const uint4*)ub, (const uint4*)ib, (uint4*)meanL1b, need_i, need_u);

  // layer-1 item + user GEMM/LN on compact row lists (ONE launch)
  k_mfma_ln2<<<GRID_I + GRID_U, 256, 0, stream>>>(
      list_i, list_u, cnt2,
      meanL1b, ib, ub, Wlb, Wrb00, Wrcb,
      bl + 0 * NH, ln_g + 1 * NH, ln_b + 1 * NH, xi1b,
      bc, ln_g + 0 * NH, ln_b + 0 * NH, xu1b);

  // layer-2 aggregation at targets only (item update is dead code)
  k_agg_tgt<<<AGGT_G * 8, 256, 0, stream>>>(
      tgt, offs, cnt, esrc, (const uint4*)xu1b, (const uint4*)xi1b,
      mrev2, mfol2, xsel2);

  // layer-2 user GEMM/LN + final MLP fused (h2 stays in LDS)
  k_gemm_mlp<<<NTGT / 64, 256, 0, stream>>>(
      mrev2, Wl + (1 * 3 + 1) * NHNH,
      mfol2, Wl + (1 * 3 + 2) * NHNH,
      xsel2, Wrc + NHNH,
      bc + NH, ln_g + 2 * NH, ln_b + 2 * NH,
      W1, b1, W2, b2, outp, NTGT);
}